// Round 5
// baseline (555.127 us; speedup 1.0000x reference)
//
#include <hip/hip_runtime.h>

// Problem constants (fixed by the reference)
#define N_NODES   100000
#define N_EDGES   1600000
#define IN_CH     16
#define HID_CH    64
#define OUT_CH    128
#define N_GRAPHS  128

// ---------------- kernels ----------------

__global__ void k_init(float* deg, float* h1, float* out2) {
    int i = blockIdx.x * blockDim.x + threadIdx.x;
    int st = gridDim.x * blockDim.x;
    for (int n = i; n < N_NODES; n += st) deg[n] = 1.0f;   // self-loop count
    const int H1N = N_NODES * HID_CH;
    for (int n = i; n < H1N; n += st) h1[n] = 0.0f;
    for (int n = i; n < N_GRAPHS * OUT_CH; n += st) out2[n] = 0.0f;
}

// Full edge pass: in-degree histogram at dst.
__global__ void k_deg(const int* __restrict__ dst, float* deg) {
    int i = blockIdx.x * blockDim.x + threadIdx.x;
    int st = gridDim.x * blockDim.x;
    for (int e = i; e < N_EDGES; e += st) atomicAdd(&deg[dst[e]], 1.0f);
}

// deg -> rsqrt(deg) in place (deg >= 1 always)
__global__ void k_dis(float* deg) {
    int i = blockIdx.x * blockDim.x + threadIdx.x;
    int st = gridDim.x * blockDim.x;
    for (int n = i; n < N_NODES; n += st) deg[n] = rsqrtf(deg[n]);
}

// Dense layer-1 edge scatter: one wave per edge; lane = hidden channel.
__global__ void k_l1_edge(const int* __restrict__ src, const int* __restrict__ dst,
                          const float* __restrict__ x, const float* __restrict__ W1,
                          const float* __restrict__ dis, float* h1) {
    __shared__ float w1s[IN_CH * HID_CH];
    for (int t = threadIdx.x; t < IN_CH * HID_CH; t += blockDim.x) w1s[t] = W1[t];
    __syncthreads();
    int lane = threadIdx.x & 63;
    int wid = blockIdx.x * (blockDim.x >> 6) + (threadIdx.x >> 6);
    int nw = gridDim.x * (blockDim.x >> 6);
    for (int e = wid; e < N_EDGES; e += nw) {
        int s = src[e];
        int d = dst[e];
        float norm = dis[s] * dis[d];
        float xv = (lane < IN_CH) ? x[s * IN_CH + lane] : 0.0f;
        float t = 0.0f;
#pragma unroll
        for (int c = 0; c < IN_CH; ++c)
            t += __shfl(xv, c, 64) * w1s[c * HID_CH + lane];
        atomicAdd(&h1[(size_t)d * HID_CH + lane], t * norm);
    }
}

// Dense layer-1 self-loop + bias + ReLU: one wave per node.
__global__ void k_l1_self(const float* __restrict__ x, const float* __restrict__ W1,
                          const float* __restrict__ b1, const float* __restrict__ dis,
                          float* h1) {
    __shared__ float w1s[IN_CH * HID_CH];
    for (int t = threadIdx.x; t < IN_CH * HID_CH; t += blockDim.x) w1s[t] = W1[t];
    __syncthreads();
    int lane = threadIdx.x & 63;
    int wid = blockIdx.x * (blockDim.x >> 6) + (threadIdx.x >> 6);
    int nw = gridDim.x * (blockDim.x >> 6);
    for (int n = wid; n < N_NODES; n += nw) {
        float xv = (lane < IN_CH) ? x[n * IN_CH + lane] : 0.0f;
        float t = 0.0f;
#pragma unroll
        for (int c = 0; c < IN_CH; ++c)
            t += __shfl(xv, c, 64) * w1s[c * HID_CH + lane];
        float dn = dis[n];
        size_t off = (size_t)n * HID_CH + lane;
        float v = h1[off] + t * dn * dn + b1[lane];
        h1[off] = v > 0.0f ? v : 0.0f;
    }
}

// Literal layer-2: full edge scan, one wave per edge. Ballot-match dst against
// ALL 128 central values; on match, add the message to EVERY matching row
// (duplicate centrals each accumulate the full sum — no dedup logic at all).
__global__ void k_l2_scan(const int* __restrict__ src, const int* __restrict__ dst,
                          const int* __restrict__ ptr,
                          const float* __restrict__ h1, const float* __restrict__ W2,
                          const float* __restrict__ dis, float* out2) {
    __shared__ int cent[128];
    if (threadIdx.x < 128) cent[threadIdx.x] = ptr[threadIdx.x];
    __syncthreads();
    int lane = threadIdx.x & 63;
    int c0 = cent[lane];
    int c1 = cent[lane + 64];
    int wid = blockIdx.x * (blockDim.x >> 6) + (threadIdx.x >> 6);
    int nw = gridDim.x * (blockDim.x >> 6);
    for (int e = wid; e < N_EDGES; e += nw) {
        int d = dst[e];
        unsigned long long b0 = __ballot(c0 == d);
        unsigned long long b1 = __ballot(c1 == d);
        if (!(b0 | b1)) continue;
        int s = src[e];
        float norm = dis[s] * dis[d];
        const float* hrow = &h1[(size_t)s * HID_CH];
        float a0 = 0.0f, a1 = 0.0f;
#pragma unroll 8
        for (int j = 0; j < HID_CH; ++j) {
            float hv = hrow[j];
            a0 += hv * W2[j * OUT_CH + lane];
            a1 += hv * W2[j * OUT_CH + lane + 64];
        }
        a0 *= norm; a1 *= norm;
        while (b0) {
            int r = __ffsll((unsigned long long)b0) - 1; b0 &= b0 - 1;
            atomicAdd(&out2[r * OUT_CH + lane], a0);
            atomicAdd(&out2[r * OUT_CH + lane + 64], a1);
        }
        while (b1) {
            int r = __ffsll((unsigned long long)b1) - 1 + 64; b1 &= b1 - 1;
            atomicAdd(&out2[r * OUT_CH + lane], a0);
            atomicAdd(&out2[r * OUT_CH + lane + 64], a1);
        }
    }
}

// Layer-2 self-loop: every output row independently (duplicates included).
__global__ void k_l2_self(const int* __restrict__ ptr, const float* __restrict__ h1,
                          const float* __restrict__ W2, const float* __restrict__ dis,
                          float* out2) {
    int lane = threadIdx.x & 63;
    int wid = blockIdx.x * (blockDim.x >> 6) + (threadIdx.x >> 6);
    int nw = gridDim.x * (blockDim.x >> 6);
    for (int i = wid; i < N_GRAPHS; i += nw) {
        int c = ptr[i];
        float dn = dis[c];
        float d2 = dn * dn;
        const float* hrow = &h1[(size_t)c * HID_CH];
        float a0 = 0.0f, a1 = 0.0f;
#pragma unroll 8
        for (int j = 0; j < HID_CH; ++j) {
            float hv = hrow[j];
            a0 += hv * W2[j * OUT_CH + lane];
            a1 += hv * W2[j * OUT_CH + lane + 64];
        }
        out2[i * OUT_CH + lane] += a0 * d2;
        out2[i * OUT_CH + lane + 64] += a1 * d2;
    }
}

// Final: add bias, write d_out (fp32). No dedup/copy logic.
__global__ void k_final(const float* __restrict__ out2, const float* __restrict__ b2,
                        float* out) {
    int idx = blockIdx.x * blockDim.x + threadIdx.x;
    if (idx >= N_GRAPHS * OUT_CH) return;
    out[idx] = out2[idx] + b2[idx & 127];
}

// ---------------- launch ----------------

extern "C" void kernel_launch(void* const* d_in, const int* in_sizes, int n_in,
                              void* d_out, int out_size, void* d_ws, size_t ws_size,
                              hipStream_t stream) {
    const float* x  = (const float*)d_in[0];    // fp32 (validated: bf16 reads -> NaN)
    const int* edge = (const int*)d_in[1];      // int32 (validated: int64 reads fault)
    const int* src  = edge;
    const int* dst  = edge + N_EDGES;
    const int* ptr  = (const int*)d_in[2];
    const float* W1 = (const float*)d_in[3];
    const float* b1 = (const float*)d_in[4];
    const float* W2 = (const float*)d_in[5];
    const float* b2 = (const float*)d_in[6];
    float* out = (float*)d_out;

    // workspace: deg 0.4MB + h1 25.6MB + out2 64KB  (round-3 footprint, known-safe)
    char* p = (char*)d_ws;
    auto alloc = [&](size_t bytes) {
        char* r = p; p += (bytes + 255) & ~size_t(255); return r;
    };
    float* deg  = (float*)alloc((size_t)N_NODES * sizeof(float));   // becomes dis
    float* h1   = (float*)alloc((size_t)N_NODES * HID_CH * sizeof(float));
    float* out2 = (float*)alloc((size_t)N_GRAPHS * OUT_CH * sizeof(float));

    hipLaunchKernelGGL(k_init, dim3(2048), dim3(256), 0, stream, deg, h1, out2);
    hipLaunchKernelGGL(k_deg, dim3(1024), dim3(256), 0, stream, dst, deg);
    hipLaunchKernelGGL(k_dis, dim3(512), dim3(256), 0, stream, deg);
    hipLaunchKernelGGL(k_l1_edge, dim3(2048), dim3(256), 0, stream,
                       src, dst, x, W1, deg, h1);
    hipLaunchKernelGGL(k_l1_self, dim3(1024), dim3(256), 0, stream,
                       x, W1, b1, deg, h1);
    hipLaunchKernelGGL(k_l2_scan, dim3(2048), dim3(256), 0, stream,
                       src, dst, ptr, h1, W2, deg, out2);
    hipLaunchKernelGGL(k_l2_self, dim3(8), dim3(256), 0, stream,
                       ptr, h1, W2, deg, out2);
    hipLaunchKernelGGL(k_final, dim3((N_GRAPHS * OUT_CH + 255) / 256), dim3(256), 0, stream,
                       out2, b2, out);
}

// Round 6
// 404.913 us; speedup vs baseline: 1.3710x; 1.3710x over previous
//
#include <hip/hip_runtime.h>

// Problem constants (fixed by the reference)
#define N_NODES   100000
#define N_EDGES   1600000
#define IN_CH     16
#define HID_CH    64
#define OUT_CH    128
#define N_GRAPHS  128

// Capacities. Expected: slots ~2.2K, list1 ~35K, list2 ~2K. 4-8x margins.
#define CAPS  8192
#define CAP1  131072
#define CAP2  16384

#define BM_WORDS ((N_NODES + 31) / 32)   // 3125 words = 12.5 KB LDS bitmap

// ---------------- kernels ----------------

__global__ void k_init(float* deg, int* map1, float* h1, float* out2, int* cnt) {
    int i = blockIdx.x * blockDim.x + threadIdx.x;
    int st = gridDim.x * blockDim.x;
    for (int n = i; n < N_NODES; n += st) { deg[n] = 1.0f; map1[n] = -1; }
    const int H1N = CAPS * HID_CH;                    // 2 MB
    for (int n = i; n < H1N; n += st) h1[n] = 0.0f;
    for (int n = i; n < N_GRAPHS * OUT_CH; n += st) out2[n] = 0.0f;
    if (i < 8) cnt[i] = 0;
}

// Mark central nodes as needing h1 (-2 = needed, benign same-value races).
__global__ void k_central(const int* __restrict__ ptr, int* map1) {
    int i = threadIdx.x;
    if (i < N_GRAPHS) map1[ptr[i]] = -2;
}

// Full edge pass: degree histogram + central-dst edge detection via LDS bitmap.
__global__ void k_pass1(const int* __restrict__ src, const int* __restrict__ dst,
                        const int* __restrict__ ptr,
                        float* deg, int* map1, int* list2, int* cnt) {
    __shared__ unsigned int bm[BM_WORDS];
    for (int t = threadIdx.x; t < BM_WORDS; t += blockDim.x) bm[t] = 0u;
    __syncthreads();
    if (threadIdx.x < N_GRAPHS) {
        int c = ptr[threadIdx.x];
        atomicOr(&bm[c >> 5], 1u << (c & 31));
    }
    __syncthreads();
    int i = blockIdx.x * blockDim.x + threadIdx.x;
    int st = gridDim.x * blockDim.x;
    for (int e = i; e < N_EDGES; e += st) {
        int d = dst[e];
        atomicAdd(&deg[d], 1.0f);
        if ((bm[d >> 5] >> (d & 31)) & 1u) {
            map1[src[e]] = -2;                 // benign same-value race
            int idx = atomicAdd(&cnt[2], 1);
            if (idx < CAP2) list2[idx] = e;
        }
    }
}

// deg -> rsqrt(deg) in place; assign compact slots to needed nodes.
__global__ void k_node(float* deg, int* map1, int* slotnode, int* cnt) {
    int i = blockIdx.x * blockDim.x + threadIdx.x;
    int st = gridDim.x * blockDim.x;
    for (int n = i; n < N_NODES; n += st) {
        deg[n] = rsqrtf(deg[n]);               // deg >= 1 always
        if (map1[n] == -2) {
            int s = atomicAdd(&cnt[0], 1);
            if (s < CAPS) { map1[n] = s; slotnode[s] = n; }
            else          { map1[n] = 0; }     // overflow: clamp, never fault
        }
    }
}

// Full edge pass: list edges whose dst has an h1 slot.
__global__ void k_pass2(const int* __restrict__ dst, const int* __restrict__ map1,
                        int* list1, int* cnt) {
    int i = blockIdx.x * blockDim.x + threadIdx.x;
    int st = gridDim.x * blockDim.x;
    for (int e = i; e < N_EDGES; e += st) {
        if (map1[dst[e]] >= 0) {
            int idx = atomicAdd(&cnt[1], 1);
            if (idx < CAP1) list1[idx] = e;
        }
    }
}

// Sparse layer-1 edge scatter: one wave per listed edge; lane = hidden channel.
__global__ void k_l1_edge(const int* __restrict__ src, const int* __restrict__ dst,
                          const float* __restrict__ x, const float* __restrict__ W1,
                          const float* __restrict__ dis, const int* __restrict__ map1,
                          const int* __restrict__ list1, const int* __restrict__ cnt,
                          float* h1) {
    __shared__ float w1s[IN_CH * HID_CH];
    for (int t = threadIdx.x; t < IN_CH * HID_CH; t += blockDim.x) w1s[t] = W1[t];
    __syncthreads();
    int lane = threadIdx.x & 63;
    int wid = blockIdx.x * (blockDim.x >> 6) + (threadIdx.x >> 6);
    int nw = gridDim.x * (blockDim.x >> 6);
    int n1 = min(cnt[1], CAP1);
    for (int w = wid; w < n1; w += nw) {
        int e = list1[w];
        int s = src[e];
        int d = dst[e];
        int slot = map1[d];                    // >= 0 by construction
        float norm = dis[s] * dis[d];
        float xv = (lane < IN_CH) ? x[s * IN_CH + lane] : 0.0f;
        float t = 0.0f;
#pragma unroll
        for (int c = 0; c < IN_CH; ++c)
            t += __shfl(xv, c, 64) * w1s[c * HID_CH + lane];
        atomicAdd(&h1[(size_t)slot * HID_CH + lane], t * norm);
    }
}

// Sparse layer-1 self-loop + bias + ReLU: one wave per slot.
__global__ void k_l1_self(const float* __restrict__ x, const float* __restrict__ W1,
                          const float* __restrict__ b1, const float* __restrict__ dis,
                          const int* __restrict__ slotnode, const int* __restrict__ cnt,
                          float* h1) {
    __shared__ float w1s[IN_CH * HID_CH];
    for (int t = threadIdx.x; t < IN_CH * HID_CH; t += blockDim.x) w1s[t] = W1[t];
    __syncthreads();
    int lane = threadIdx.x & 63;
    int wid = blockIdx.x * (blockDim.x >> 6) + (threadIdx.x >> 6);
    int nw = gridDim.x * (blockDim.x >> 6);
    int nS = min(cnt[0], CAPS);
    for (int sl = wid; sl < nS; sl += nw) {
        int n = slotnode[sl];
        float xv = (lane < IN_CH) ? x[n * IN_CH + lane] : 0.0f;
        float t = 0.0f;
#pragma unroll
        for (int c = 0; c < IN_CH; ++c)
            t += __shfl(xv, c, 64) * w1s[c * HID_CH + lane];
        float dn = dis[n];
        size_t off = (size_t)sl * HID_CH + lane;
        float v = h1[off] + t * dn * dn + b1[lane];
        h1[off] = v > 0.0f ? v : 0.0f;
    }
}

// Layer-2 over listed central-dst edges: one wave per edge. Row resolution via
// ballot against all 128 central values (round-5 validated); every matching row
// accumulates the full message independently (duplicates included).
__global__ void k_l2_edge(const int* __restrict__ src, const int* __restrict__ dst,
                          const int* __restrict__ ptr,
                          const float* __restrict__ h1, const float* __restrict__ W2,
                          const float* __restrict__ dis, const int* __restrict__ map1,
                          const int* __restrict__ list2, const int* __restrict__ cnt,
                          float* out2) {
    __shared__ int cent[128];
    if (threadIdx.x < 128) cent[threadIdx.x] = ptr[threadIdx.x];
    __syncthreads();
    int lane = threadIdx.x & 63;
    int c0 = cent[lane];
    int c1 = cent[lane + 64];
    int wid = blockIdx.x * (blockDim.x >> 6) + (threadIdx.x >> 6);
    int nw = gridDim.x * (blockDim.x >> 6);
    int n2 = min(cnt[2], CAP2);
    for (int w = wid; w < n2; w += nw) {
        int e = list2[w];
        int d = dst[e];
        unsigned long long b0 = __ballot(c0 == d);
        unsigned long long b1 = __ballot(c1 == d);
        if (!(b0 | b1)) continue;              // cannot happen, defensive
        int s = src[e];
        int slot = map1[s]; if (slot < 0) slot = 0;   // marked in pass1
        float norm = dis[s] * dis[d];
        const float* hrow = &h1[(size_t)slot * HID_CH];
        float a0 = 0.0f, a1 = 0.0f;
#pragma unroll 8
        for (int j = 0; j < HID_CH; ++j) {
            float hv = hrow[j];
            a0 += hv * W2[j * OUT_CH + lane];
            a1 += hv * W2[j * OUT_CH + lane + 64];
        }
        a0 *= norm; a1 *= norm;
        while (b0) {
            int r = __ffsll((unsigned long long)b0) - 1; b0 &= b0 - 1;
            atomicAdd(&out2[r * OUT_CH + lane], a0);
            atomicAdd(&out2[r * OUT_CH + lane + 64], a1);
        }
        while (b1) {
            int r = __ffsll((unsigned long long)b1) - 1 + 64; b1 &= b1 - 1;
            atomicAdd(&out2[r * OUT_CH + lane], a0);
            atomicAdd(&out2[r * OUT_CH + lane + 64], a1);
        }
    }
}

// Layer-2 self-loop: every output row independently (duplicates included).
__global__ void k_l2_self(const int* __restrict__ ptr, const float* __restrict__ h1,
                          const float* __restrict__ W2, const float* __restrict__ dis,
                          const int* __restrict__ map1, float* out2) {
    int lane = threadIdx.x & 63;
    int wid = blockIdx.x * (blockDim.x >> 6) + (threadIdx.x >> 6);
    int nw = gridDim.x * (blockDim.x >> 6);
    for (int i = wid; i < N_GRAPHS; i += nw) {
        int c = ptr[i];
        int slot = map1[c]; if (slot < 0) slot = 0;   // centrals always marked
        float dn = dis[c];
        float d2 = dn * dn;
        const float* hrow = &h1[(size_t)slot * HID_CH];
        float a0 = 0.0f, a1 = 0.0f;
#pragma unroll 8
        for (int j = 0; j < HID_CH; ++j) {
            float hv = hrow[j];
            a0 += hv * W2[j * OUT_CH + lane];
            a1 += hv * W2[j * OUT_CH + lane + 64];
        }
        out2[i * OUT_CH + lane] += a0 * d2;
        out2[i * OUT_CH + lane + 64] += a1 * d2;
    }
}

// Final: add bias, write d_out (fp32).
__global__ void k_final(const float* __restrict__ out2, const float* __restrict__ b2,
                        float* out) {
    int idx = blockIdx.x * blockDim.x + threadIdx.x;
    if (idx >= N_GRAPHS * OUT_CH) return;
    out[idx] = out2[idx] + b2[idx & 127];
}

// ---------------- launch ----------------

extern "C" void kernel_launch(void* const* d_in, const int* in_sizes, int n_in,
                              void* d_out, int out_size, void* d_ws, size_t ws_size,
                              hipStream_t stream) {
    const float* x  = (const float*)d_in[0];    // fp32 (validated: bf16 reads -> NaN)
    const int* edge = (const int*)d_in[1];      // int32 (validated: int64 reads fault)
    const int* src  = edge;
    const int* dst  = edge + N_EDGES;
    const int* ptr  = (const int*)d_in[2];
    const float* W1 = (const float*)d_in[3];
    const float* b1 = (const float*)d_in[4];
    const float* W2 = (const float*)d_in[5];
    const float* b2 = (const float*)d_in[6];
    float* out = (float*)d_out;

    // workspace ~3.5 MB (round-5 used 26 MB successfully)
    char* p = (char*)d_ws;
    auto alloc = [&](size_t bytes) {
        char* r = p; p += (bytes + 255) & ~size_t(255); return r;
    };
    float* deg      = (float*)alloc((size_t)N_NODES * sizeof(float));  // becomes dis
    int*   map1     = (int*)  alloc((size_t)N_NODES * sizeof(int));
    int*   slotnode = (int*)  alloc((size_t)CAPS * sizeof(int));
    int*   list1    = (int*)  alloc((size_t)CAP1 * sizeof(int));
    int*   list2    = (int*)  alloc((size_t)CAP2 * sizeof(int));
    float* h1       = (float*)alloc((size_t)CAPS * HID_CH * sizeof(float));
    float* out2     = (float*)alloc((size_t)N_GRAPHS * OUT_CH * sizeof(float));
    int*   cnt      = (int*)  alloc(256);

    hipLaunchKernelGGL(k_init, dim3(1024), dim3(256), 0, stream,
                       deg, map1, h1, out2, cnt);
    hipLaunchKernelGGL(k_central, dim3(1), dim3(128), 0, stream, ptr, map1);
    hipLaunchKernelGGL(k_pass1, dim3(1024), dim3(256), 0, stream,
                       src, dst, ptr, deg, map1, list2, cnt);
    hipLaunchKernelGGL(k_node, dim3(512), dim3(256), 0, stream,
                       deg, map1, slotnode, cnt);
    hipLaunchKernelGGL(k_pass2, dim3(1024), dim3(256), 0, stream,
                       dst, map1, list1, cnt);
    hipLaunchKernelGGL(k_l1_edge, dim3(512), dim3(256), 0, stream,
                       src, dst, x, W1, deg, map1, list1, cnt, h1);
    hipLaunchKernelGGL(k_l1_self, dim3(128), dim3(256), 0, stream,
                       x, W1, b1, deg, slotnode, cnt, h1);
    hipLaunchKernelGGL(k_l2_edge, dim3(64), dim3(256), 0, stream,
                       src, dst, ptr, h1, W2, deg, map1, list2, cnt, out2);
    hipLaunchKernelGGL(k_l2_self, dim3(8), dim3(256), 0, stream,
                       ptr, h1, W2, deg, map1, out2);
    hipLaunchKernelGGL(k_final, dim3((N_GRAPHS * OUT_CH + 255) / 256), dim3(256), 0, stream,
                       out2, b2, out);
}

// Round 7
// 173.544 us; speedup vs baseline: 3.1988x; 2.3332x over previous
//
#include <hip/hip_runtime.h>

// Problem constants (fixed by the reference)
#define N_NODES   100000
#define N_EDGES   1600000
#define IN_CH     16
#define HID_CH    64
#define OUT_CH    128
#define N_GRAPHS  128

// Capacities. Expected: slots ~2.2K, list2 ~2K.
#define CAPS  8192
#define CAP2  16384

#define BM_WORDS ((N_NODES + 31) / 32)          // 3125 words = 12.5 KB bitmap

#define P1_BLOCKS 2048
#define P1_CHUNK  ((N_EDGES + P1_BLOCKS - 1) / P1_BLOCKS)   // 782 edges/block

// ---------------- kernels ----------------

__global__ void k_init(float* deg, int* map1, float* h1, float* out2, int* cnt,
                       unsigned int* cbm, unsigned int* mbm) {
    int i = blockIdx.x * blockDim.x + threadIdx.x;
    int st = gridDim.x * blockDim.x;
    for (int n = i; n < N_NODES; n += st) { deg[n] = 1.0f; map1[n] = -1; }
    for (int n = i; n < CAPS * HID_CH; n += st) h1[n] = 0.0f;
    for (int n = i; n < N_GRAPHS * OUT_CH; n += st) out2[n] = 0.0f;
    for (int n = i; n < BM_WORDS; n += st) { cbm[n] = 0u; mbm[n] = 0u; }
    if (i < 8) cnt[i] = 0;
}

// Mark central nodes (map1=-2) and build the central bitmap.
__global__ void k_central(const int* __restrict__ ptr, int* map1,
                          unsigned int* cbm) {
    int i = threadIdx.x;
    if (i < N_GRAPHS) {
        int c = ptr[i];
        map1[c] = -2;
        atomicOr(&cbm[c >> 5], 1u << (c & 31));
    }
}

// Full edge pass: degree histogram + central-dst edge detection (bitmap test).
// list2 built via per-block LDS buffer -> ONE global counter atomic per block.
__global__ void __launch_bounds__(256) k_pass1(
        const int* __restrict__ src, const int* __restrict__ dst,
        const unsigned int* __restrict__ cbm,
        float* deg, int* map1, int* list2, int* cnt) {
    __shared__ int lbuf[P1_CHUNK];
    __shared__ int lcnt, gbase;
    if (threadIdx.x == 0) lcnt = 0;
    __syncthreads();
    int e0 = blockIdx.x * P1_CHUNK;
    int e1 = min(e0 + P1_CHUNK, N_EDGES);
    for (int e = e0 + (int)threadIdx.x; e < e1; e += blockDim.x) {
        int d = dst[e];
        atomicAdd(&deg[d], 1.0f);
        if ((cbm[d >> 5] >> (d & 31)) & 1u) {
            map1[src[e]] = -2;                  // benign same-value race
            int idx = atomicAdd(&lcnt, 1);      // LDS atomic, ~2/block
            lbuf[idx] = e;                      // idx < P1_CHUNK by construction
        }
    }
    __syncthreads();
    if (threadIdx.x == 0) gbase = atomicAdd(&cnt[2], lcnt);
    __syncthreads();
    for (int t = threadIdx.x; t < lcnt; t += blockDim.x) {
        int gi = gbase + t;
        if (gi < CAP2) list2[gi] = lbuf[t];
    }
}

// deg -> rsqrt(deg) in place; wave-aggregated slot assignment for marked nodes;
// set marked-node bitmap.
__global__ void k_node(float* deg, int* map1, int* slotnode, int* cnt,
                       unsigned int* mbm) {
    int lane = threadIdx.x & 63;
    int i = blockIdx.x * blockDim.x + threadIdx.x;
    int st = gridDim.x * blockDim.x;
    for (int n = i; n < N_NODES; n += st) {
        deg[n] = rsqrtf(deg[n]);                // deg >= 1 always
        bool need = (map1[n] == -2);
        unsigned long long mk = __ballot(need);
        if (mk) {
            int leader = __ffsll((long long)mk) - 1;
            int base = 0;
            if (lane == leader) base = atomicAdd(&cnt[0], __popcll(mk));
            base = __shfl(base, leader, 64);
            if (need) {
                int s = base + (int)__popcll(mk & ((1ull << lane) - 1));
                if (s < CAPS) { map1[n] = s; slotnode[s] = n; }
                else          { map1[n] = 0; }  // overflow: clamp, never fault
                atomicOr(&mbm[n >> 5], 1u << (n & 31));
            }
        }
    }
}

// Fused layer-1: full edge scan, 64 edges per wave iteration. Bitmap test
// (L1-resident 12.5KB) filters ~97.8% of edges; matched edges get a
// cooperative 16->64 GEMV + h1 atomic scatter. No counter atomics, no lists.
__global__ void __launch_bounds__(256) k_l1_fused(
        const int* __restrict__ src, const int* __restrict__ dst,
        const float* __restrict__ x, const float* __restrict__ W1,
        const float* __restrict__ dis, const int* __restrict__ map1,
        const unsigned int* __restrict__ mbm, float* h1) {
    __shared__ float w1s[IN_CH * HID_CH];
    for (int t = threadIdx.x; t < IN_CH * HID_CH; t += blockDim.x) w1s[t] = W1[t];
    __syncthreads();
    int lane = threadIdx.x & 63;
    int gwid = blockIdx.x * (blockDim.x >> 6) + (threadIdx.x >> 6);
    int nw = gridDim.x * (blockDim.x >> 6);
    for (int base = gwid * 64; base < N_EDGES; base += nw * 64) {
        int e = base + lane;
        int d = -1, slot = -1;
        if (e < N_EDGES) {
            d = dst[e];
            if ((mbm[d >> 5] >> (d & 31)) & 1u) slot = map1[d];
        }
        unsigned long long m = __ballot(slot >= 0);
        while (m) {
            int l = __ffsll((long long)m) - 1; m &= m - 1;
            int el = base + l;
            int dl = __shfl(d, l, 64);
            int sl = __shfl(slot, l, 64);
            int s  = src[el];                   // wave-uniform load
            float norm = dis[s] * dis[dl];
            float xv = (lane < IN_CH) ? x[s * IN_CH + lane] : 0.0f;
            float t = 0.0f;
#pragma unroll
            for (int c = 0; c < IN_CH; ++c)
                t += __shfl(xv, c, 64) * w1s[c * HID_CH + lane];
            atomicAdd(&h1[(size_t)sl * HID_CH + lane], t * norm);
        }
    }
}

// Layer-1 self-loop + bias + ReLU: one wave per slot.
__global__ void k_l1_self(const float* __restrict__ x, const float* __restrict__ W1,
                          const float* __restrict__ b1, const float* __restrict__ dis,
                          const int* __restrict__ slotnode, const int* __restrict__ cnt,
                          float* h1) {
    __shared__ float w1s[IN_CH * HID_CH];
    for (int t = threadIdx.x; t < IN_CH * HID_CH; t += blockDim.x) w1s[t] = W1[t];
    __syncthreads();
    int lane = threadIdx.x & 63;
    int wid = blockIdx.x * (blockDim.x >> 6) + (threadIdx.x >> 6);
    int nw = gridDim.x * (blockDim.x >> 6);
    int nS = min(cnt[0], CAPS);
    for (int sl = wid; sl < nS; sl += nw) {
        int n = slotnode[sl];
        float xv = (lane < IN_CH) ? x[n * IN_CH + lane] : 0.0f;
        float t = 0.0f;
#pragma unroll
        for (int c = 0; c < IN_CH; ++c)
            t += __shfl(xv, c, 64) * w1s[c * HID_CH + lane];
        float dn = dis[n];
        size_t off = (size_t)sl * HID_CH + lane;
        float v = h1[off] + t * dn * dn + b1[lane];
        h1[off] = v > 0.0f ? v : 0.0f;
    }
}

// Layer-2: listed central-dst edges (ballot row-resolution, duplicates each
// accumulate) + per-row self-loops appended as extra work items. All atomic.
__global__ void k_l2(const int* __restrict__ src, const int* __restrict__ dst,
                     const int* __restrict__ ptr,
                     const float* __restrict__ h1, const float* __restrict__ W2,
                     const float* __restrict__ dis, const int* __restrict__ map1,
                     const int* __restrict__ list2, const int* __restrict__ cnt,
                     float* out2) {
    __shared__ int cent[128];
    if (threadIdx.x < 128) cent[threadIdx.x] = ptr[threadIdx.x];
    __syncthreads();
    int lane = threadIdx.x & 63;
    int c0 = cent[lane];
    int c1v = cent[lane + 64];
    int wid = blockIdx.x * (blockDim.x >> 6) + (threadIdx.x >> 6);
    int nw = gridDim.x * (blockDim.x >> 6);
    int n2 = min(cnt[2], CAP2);
    for (int w = wid; w < n2 + N_GRAPHS; w += nw) {
        int s, d, selfrow = -1;
        if (w < n2) {
            int e = list2[w];
            s = src[e]; d = dst[e];
        } else {
            selfrow = w - n2;
            s = cent[selfrow]; d = s;
        }
        int slot = map1[s]; if (slot < 0) slot = 0;   // always marked
        float norm = dis[s] * dis[d];
        const float* hrow = &h1[(size_t)slot * HID_CH];
        float a0 = 0.0f, a1 = 0.0f;
#pragma unroll 8
        for (int j = 0; j < HID_CH; ++j) {
            float hv = hrow[j];
            a0 += hv * W2[j * OUT_CH + lane];
            a1 += hv * W2[j * OUT_CH + lane + 64];
        }
        a0 *= norm; a1 *= norm;
        if (selfrow >= 0) {
            atomicAdd(&out2[selfrow * OUT_CH + lane], a0);
            atomicAdd(&out2[selfrow * OUT_CH + lane + 64], a1);
        } else {
            unsigned long long b0 = __ballot(c0 == d);
            unsigned long long b1 = __ballot(c1v == d);
            while (b0) {
                int r = __ffsll((long long)b0) - 1; b0 &= b0 - 1;
                atomicAdd(&out2[r * OUT_CH + lane], a0);
                atomicAdd(&out2[r * OUT_CH + lane + 64], a1);
            }
            while (b1) {
                int r = __ffsll((long long)b1) - 1 + 64; b1 &= b1 - 1;
                atomicAdd(&out2[r * OUT_CH + lane], a0);
                atomicAdd(&out2[r * OUT_CH + lane + 64], a1);
            }
        }
    }
}

// Final: add bias, write d_out (fp32).
__global__ void k_final(const float* __restrict__ out2, const float* __restrict__ b2,
                        float* out) {
    int idx = blockIdx.x * blockDim.x + threadIdx.x;
    if (idx >= N_GRAPHS * OUT_CH) return;
    out[idx] = out2[idx] + b2[idx & 127];
}

// ---------------- launch ----------------

extern "C" void kernel_launch(void* const* d_in, const int* in_sizes, int n_in,
                              void* d_out, int out_size, void* d_ws, size_t ws_size,
                              hipStream_t stream) {
    const float* x  = (const float*)d_in[0];    // fp32 (validated)
    const int* edge = (const int*)d_in[1];      // int32 (validated)
    const int* src  = edge;
    const int* dst  = edge + N_EDGES;
    const int* ptr  = (const int*)d_in[2];
    const float* W1 = (const float*)d_in[3];
    const float* b1 = (const float*)d_in[4];
    const float* W2 = (const float*)d_in[5];
    const float* b2 = (const float*)d_in[6];
    float* out = (float*)d_out;

    // workspace ~3.6 MB
    char* p = (char*)d_ws;
    auto alloc = [&](size_t bytes) {
        char* r = p; p += (bytes + 255) & ~size_t(255); return r;
    };
    float* deg      = (float*)alloc((size_t)N_NODES * sizeof(float));  // becomes dis
    int*   map1     = (int*)  alloc((size_t)N_NODES * sizeof(int));
    int*   slotnode = (int*)  alloc((size_t)CAPS * sizeof(int));
    int*   list2    = (int*)  alloc((size_t)CAP2 * sizeof(int));
    float* h1       = (float*)alloc((size_t)CAPS * HID_CH * sizeof(float));
    float* out2     = (float*)alloc((size_t)N_GRAPHS * OUT_CH * sizeof(float));
    unsigned int* cbm = (unsigned int*)alloc((size_t)BM_WORDS * sizeof(unsigned int));
    unsigned int* mbm = (unsigned int*)alloc((size_t)BM_WORDS * sizeof(unsigned int));
    int*   cnt      = (int*)  alloc(256);

    hipLaunchKernelGGL(k_init, dim3(1024), dim3(256), 0, stream,
                       deg, map1, h1, out2, cnt, cbm, mbm);
    hipLaunchKernelGGL(k_central, dim3(1), dim3(128), 0, stream, ptr, map1, cbm);
    hipLaunchKernelGGL(k_pass1, dim3(P1_BLOCKS), dim3(256), 0, stream,
                       src, dst, cbm, deg, map1, list2, cnt);
    hipLaunchKernelGGL(k_node, dim3(512), dim3(256), 0, stream,
                       deg, map1, slotnode, cnt, mbm);
    hipLaunchKernelGGL(k_l1_fused, dim3(1024), dim3(256), 0, stream,
                       src, dst, x, W1, deg, map1, mbm, h1);
    hipLaunchKernelGGL(k_l1_self, dim3(128), dim3(256), 0, stream,
                       x, W1, b1, deg, slotnode, cnt, h1);
    hipLaunchKernelGGL(k_l2, dim3(64), dim3(256), 0, stream,
                       src, dst, ptr, h1, W2, deg, map1, list2, cnt, out2);
    hipLaunchKernelGGL(k_final, dim3((N_GRAPHS * OUT_CH + 255) / 256), dim3(256), 0, stream,
                       out2, b2, out);
}

// Round 8
// 159.120 us; speedup vs baseline: 3.4887x; 1.0906x over previous
//
#include <hip/hip_runtime.h>

// Problem constants (fixed by the reference)
#define N_NODES   100000
#define N_EDGES   1600000
#define IN_CH     16
#define HID_CH    64
#define OUT_CH    128
#define N_GRAPHS  128
#define NXCD      8

// Capacities. Expected: slots ~2.2K, list2 ~2K.
#define CAPS  8192
#define CAP2  16384

#define BM_WORDS ((N_NODES + 31) / 32)          // 3125 words = 12.5 KB bitmap

#define P1_BLOCKS 2048
#define P1_CHUNK  ((N_EDGES + P1_BLOCKS - 1) / P1_BLOCKS)   // 782 edges/block

// Physical XCD id (wave-uniform). HW-verified readable on gfx950 (m09).
__device__ __forceinline__ unsigned xcd_id() {
    unsigned x;
    asm volatile("s_getreg_b32 %0, hwreg(HW_REG_XCC_ID)" : "=s"(x));
    return x & (NXCD - 1);
}

// ---------------- kernels ----------------

__global__ void k_init(unsigned int* degX, int* map1, float* h1X, float* out2,
                       int* cnt, unsigned int* cbm, unsigned int* mbm) {
    int i = blockIdx.x * blockDim.x + threadIdx.x;
    int st = gridDim.x * blockDim.x;
    for (int n = i; n < NXCD * N_NODES; n += st) degX[n] = 0u;
    for (int n = i; n < N_NODES; n += st) map1[n] = -1;
    for (int n = i; n < NXCD * CAPS * HID_CH; n += st) h1X[n] = 0.0f;
    for (int n = i; n < N_GRAPHS * OUT_CH; n += st) out2[n] = 0.0f;
    for (int n = i; n < BM_WORDS; n += st) { cbm[n] = 0u; mbm[n] = 0u; }
    if (i < 8) cnt[i] = 0;
}

// Mark central nodes (map1=-2) and build the central bitmap.
__global__ void k_central(const int* __restrict__ ptr, int* map1,
                          unsigned int* cbm) {
    int i = threadIdx.x;
    if (i < N_GRAPHS) {
        int c = ptr[i];
        map1[c] = -2;
        atomicOr(&cbm[c >> 5], 1u << (c & 31));
    }
}

// Full edge pass: per-XCD degree histogram (XCD-local L2 atomics) +
// central-dst edge detection; list2 via LDS buffer, one global atomic/block.
__global__ void __launch_bounds__(256) k_pass1(
        const int* __restrict__ src, const int* __restrict__ dst,
        const unsigned int* __restrict__ cbm,
        unsigned int* degX, int* map1, int* list2, int* cnt) {
    __shared__ int lbuf[P1_CHUNK];
    __shared__ int lcnt, gbase;
    if (threadIdx.x == 0) lcnt = 0;
    __syncthreads();
    unsigned int* mydeg = degX + (size_t)xcd_id() * N_NODES;
    int e0 = blockIdx.x * P1_CHUNK;
    int e1 = min(e0 + P1_CHUNK, N_EDGES);
    for (int e = e0 + (int)threadIdx.x; e < e1; e += blockDim.x) {
        int d = dst[e];
        __hip_atomic_fetch_add(&mydeg[d], 1u, __ATOMIC_RELAXED,
                               __HIP_MEMORY_SCOPE_WORKGROUP);
        if ((cbm[d >> 5] >> (d & 31)) & 1u) {
            map1[src[e]] = -2;                  // benign same-value race
            int idx = atomicAdd(&lcnt, 1);      // LDS atomic
            lbuf[idx] = e;                      // idx < P1_CHUNK by construction
        }
    }
    __syncthreads();
    if (threadIdx.x == 0) gbase = atomicAdd(&cnt[2], lcnt);
    __syncthreads();
    for (int t = threadIdx.x; t < lcnt; t += blockDim.x) {
        int gi = gbase + t;
        if (gi < CAP2) list2[gi] = lbuf[t];
    }
}

// Reduce 8 degree copies -> dis = rsqrt(1+deg); wave-aggregated slot
// assignment for marked nodes; set marked-node bitmap.
__global__ void k_node(const unsigned int* __restrict__ degX, float* dis,
                       int* map1, int* slotnode, int* cnt, unsigned int* mbm) {
    int lane = threadIdx.x & 63;
    int i = blockIdx.x * blockDim.x + threadIdx.x;
    int st = gridDim.x * blockDim.x;
    for (int n = i; n < N_NODES; n += st) {
        unsigned int s8 = 1u;                   // self-loop
#pragma unroll
        for (int xx = 0; xx < NXCD; ++xx) s8 += degX[(size_t)xx * N_NODES + n];
        dis[n] = rsqrtf((float)s8);
        bool need = (map1[n] == -2);
        unsigned long long mk = __ballot(need);
        if (mk) {
            int leader = __ffsll((long long)mk) - 1;
            int base = 0;
            if (lane == leader) base = atomicAdd(&cnt[0], __popcll(mk));
            base = __shfl(base, leader, 64);
            if (need) {
                int s = base + (int)__popcll(mk & ((1ull << lane) - 1));
                if (s < CAPS) { map1[n] = s; slotnode[s] = n; }
                else          { map1[n] = 0; }  // overflow: clamp, never fault
                atomicOr(&mbm[n >> 5], 1u << (n & 31));
            }
        }
    }
}

// Fused layer-1: full edge scan, 64 edges/wave iteration; bitmap filter;
// matched edges -> cooperative 16->64 GEMV + XCD-local h1 atomics.
__global__ void __launch_bounds__(256) k_l1_fused(
        const int* __restrict__ src, const int* __restrict__ dst,
        const float* __restrict__ x, const float* __restrict__ W1,
        const float* __restrict__ dis, const int* __restrict__ map1,
        const unsigned int* __restrict__ mbm, float* h1X) {
    __shared__ float w1s[IN_CH * HID_CH];
    for (int t = threadIdx.x; t < IN_CH * HID_CH; t += blockDim.x) w1s[t] = W1[t];
    __syncthreads();
    float* myh1 = h1X + (size_t)xcd_id() * CAPS * HID_CH;
    int lane = threadIdx.x & 63;
    int gwid = blockIdx.x * (blockDim.x >> 6) + (threadIdx.x >> 6);
    int nw = gridDim.x * (blockDim.x >> 6);
    for (int base = gwid * 64; base < N_EDGES; base += nw * 64) {
        int e = base + lane;
        int d = -1, slot = -1;
        if (e < N_EDGES) {
            d = dst[e];
            if ((mbm[d >> 5] >> (d & 31)) & 1u) slot = map1[d];
        }
        unsigned long long m = __ballot(slot >= 0);
        while (m) {
            int l = __ffsll((long long)m) - 1; m &= m - 1;
            int el = base + l;
            int dl = __shfl(d, l, 64);
            int sl = __shfl(slot, l, 64);
            int s  = src[el];                   // wave-uniform load
            float norm = dis[s] * dis[dl];
            float xv = (lane < IN_CH) ? x[s * IN_CH + lane] : 0.0f;
            float t = 0.0f;
#pragma unroll
            for (int c = 0; c < IN_CH; ++c)
                t += __shfl(xv, c, 64) * w1s[c * HID_CH + lane];
            __hip_atomic_fetch_add(&myh1[(size_t)sl * HID_CH + lane], t * norm,
                                   __ATOMIC_RELAXED, __HIP_MEMORY_SCOPE_WORKGROUP);
        }
    }
}

// Reduce 8 h1 copies + self-loop + bias + ReLU -> final h1F. One wave/slot.
__global__ void k_l1_self(const float* __restrict__ x, const float* __restrict__ W1,
                          const float* __restrict__ b1, const float* __restrict__ dis,
                          const int* __restrict__ slotnode, const int* __restrict__ cnt,
                          const float* __restrict__ h1X, float* h1F) {
    __shared__ float w1s[IN_CH * HID_CH];
    for (int t = threadIdx.x; t < IN_CH * HID_CH; t += blockDim.x) w1s[t] = W1[t];
    __syncthreads();
    int lane = threadIdx.x & 63;
    int wid = blockIdx.x * (blockDim.x >> 6) + (threadIdx.x >> 6);
    int nw = gridDim.x * (blockDim.x >> 6);
    int nS = min(cnt[0], CAPS);
    for (int sl = wid; sl < nS; sl += nw) {
        int n = slotnode[sl];
        float acc = 0.0f;
#pragma unroll
        for (int xx = 0; xx < NXCD; ++xx)
            acc += h1X[((size_t)xx * CAPS + sl) * HID_CH + lane];
        float xv = (lane < IN_CH) ? x[n * IN_CH + lane] : 0.0f;
        float t = 0.0f;
#pragma unroll
        for (int c = 0; c < IN_CH; ++c)
            t += __shfl(xv, c, 64) * w1s[c * HID_CH + lane];
        float dn = dis[n];
        float v = acc + t * dn * dn + b1[lane];
        h1F[(size_t)sl * HID_CH + lane] = v > 0.0f ? v : 0.0f;
    }
}

// Layer-2: listed central-dst edges (ballot row-resolution, duplicates each
// accumulate) + per-row self-loops appended as extra work items.
__global__ void k_l2(const int* __restrict__ src, const int* __restrict__ dst,
                     const int* __restrict__ ptr,
                     const float* __restrict__ h1F, const float* __restrict__ W2,
                     const float* __restrict__ dis, const int* __restrict__ map1,
                     const int* __restrict__ list2, const int* __restrict__ cnt,
                     float* out2) {
    __shared__ int cent[128];
    if (threadIdx.x < 128) cent[threadIdx.x] = ptr[threadIdx.x];
    __syncthreads();
    int lane = threadIdx.x & 63;
    int c0 = cent[lane];
    int c1v = cent[lane + 64];
    int wid = blockIdx.x * (blockDim.x >> 6) + (threadIdx.x >> 6);
    int nw = gridDim.x * (blockDim.x >> 6);
    int n2 = min(cnt[2], CAP2);
    for (int w = wid; w < n2 + N_GRAPHS; w += nw) {
        int s, d, selfrow = -1;
        if (w < n2) {
            int e = list2[w];
            s = src[e]; d = dst[e];
        } else {
            selfrow = w - n2;
            s = cent[selfrow]; d = s;
        }
        int slot = map1[s]; if (slot < 0) slot = 0;   // always marked
        float norm = dis[s] * dis[d];
        const float* hrow = &h1F[(size_t)slot * HID_CH];
        float a0 = 0.0f, a1 = 0.0f;
#pragma unroll 8
        for (int j = 0; j < HID_CH; ++j) {
            float hv = hrow[j];
            a0 += hv * W2[j * OUT_CH + lane];
            a1 += hv * W2[j * OUT_CH + lane + 64];
        }
        a0 *= norm; a1 *= norm;
        if (selfrow >= 0) {
            atomicAdd(&out2[selfrow * OUT_CH + lane], a0);
            atomicAdd(&out2[selfrow * OUT_CH + lane + 64], a1);
        } else {
            unsigned long long b0 = __ballot(c0 == d);
            unsigned long long b1 = __ballot(c1v == d);
            while (b0) {
                int r = __ffsll((long long)b0) - 1; b0 &= b0 - 1;
                atomicAdd(&out2[r * OUT_CH + lane], a0);
                atomicAdd(&out2[r * OUT_CH + lane + 64], a1);
            }
            while (b1) {
                int r = __ffsll((long long)b1) - 1 + 64; b1 &= b1 - 1;
                atomicAdd(&out2[r * OUT_CH + lane], a0);
                atomicAdd(&out2[r * OUT_CH + lane + 64], a1);
            }
        }
    }
}

// Final: add bias, write d_out (fp32).
__global__ void k_final(const float* __restrict__ out2, const float* __restrict__ b2,
                        float* out) {
    int idx = blockIdx.x * blockDim.x + threadIdx.x;
    if (idx >= N_GRAPHS * OUT_CH) return;
    out[idx] = out2[idx] + b2[idx & 127];
}

// ---------------- launch ----------------

extern "C" void kernel_launch(void* const* d_in, const int* in_sizes, int n_in,
                              void* d_out, int out_size, void* d_ws, size_t ws_size,
                              hipStream_t stream) {
    const float* x  = (const float*)d_in[0];    // fp32 (validated)
    const int* edge = (const int*)d_in[1];      // int32 (validated)
    const int* src  = edge;
    const int* dst  = edge + N_EDGES;
    const int* ptr  = (const int*)d_in[2];
    const float* W1 = (const float*)d_in[3];
    const float* b1 = (const float*)d_in[4];
    const float* W2 = (const float*)d_in[5];
    const float* b2 = (const float*)d_in[6];
    float* out = (float*)d_out;

    // workspace ~23 MB (26 MB validated in round 3)
    char* p = (char*)d_ws;
    auto alloc = [&](size_t bytes) {
        char* r = p; p += (bytes + 255) & ~size_t(255); return r;
    };
    unsigned int* degX = (unsigned int*)alloc((size_t)NXCD * N_NODES * 4);
    float* dis      = (float*)alloc((size_t)N_NODES * sizeof(float));
    int*   map1     = (int*)  alloc((size_t)N_NODES * sizeof(int));
    int*   slotnode = (int*)  alloc((size_t)CAPS * sizeof(int));
    int*   list2    = (int*)  alloc((size_t)CAP2 * sizeof(int));
    float* h1X      = (float*)alloc((size_t)NXCD * CAPS * HID_CH * sizeof(float));
    float* h1F      = (float*)alloc((size_t)CAPS * HID_CH * sizeof(float));
    float* out2     = (float*)alloc((size_t)N_GRAPHS * OUT_CH * sizeof(float));
    unsigned int* cbm = (unsigned int*)alloc((size_t)BM_WORDS * 4);
    unsigned int* mbm = (unsigned int*)alloc((size_t)BM_WORDS * 4);
    int*   cnt      = (int*)  alloc(256);

    hipLaunchKernelGGL(k_init, dim3(2048), dim3(256), 0, stream,
                       degX, map1, h1X, out2, cnt, cbm, mbm);
    hipLaunchKernelGGL(k_central, dim3(1), dim3(128), 0, stream, ptr, map1, cbm);
    hipLaunchKernelGGL(k_pass1, dim3(P1_BLOCKS), dim3(256), 0, stream,
                       src, dst, cbm, degX, map1, list2, cnt);
    hipLaunchKernelGGL(k_node, dim3(512), dim3(256), 0, stream,
                       degX, dis, map1, slotnode, cnt, mbm);
    hipLaunchKernelGGL(k_l1_fused, dim3(1024), dim3(256), 0, stream,
                       src, dst, x, W1, dis, map1, mbm, h1X);
    hipLaunchKernelGGL(k_l1_self, dim3(128), dim3(256), 0, stream,
                       x, W1, b1, dis, slotnode, cnt, h1X, h1F);
    hipLaunchKernelGGL(k_l2, dim3(64), dim3(256), 0, stream,
                       src, dst, ptr, h1F, W2, dis, map1, list2, cnt, out2);
    hipLaunchKernelGGL(k_final, dim3((N_GRAPHS * OUT_CH + 255) / 256), dim3(256), 0, stream,
                       out2, b2, out);
}